// Round 2
// 98.127 us; speedup vs baseline: 1.0189x; 1.0189x over previous
//
#include <hip/hip_runtime.h>

#define EMB 256
#define HD 32
#define SEQ 4096
#define NSPLIT 8      // key splits across blocks (halved: Op traffic 32->16 MB round trip)
#define KRANGE 512    // keys per block (shared by its 4 waves)
#define NT (KRANGE / 32)
#define NQROW 16384   // B*S

typedef _Float16 half8 __attribute__((ext_vector_type(8)));
typedef _Float16 half4v __attribute__((ext_vector_type(4)));
typedef _Float16 half2v __attribute__((ext_vector_type(2)));
typedef float floatx4 __attribute__((ext_vector_type(4)));
typedef float floatx16 __attribute__((ext_vector_type(16)));
typedef unsigned uint2v __attribute__((ext_vector_type(2)));

#define L2E 1.44269504088896340736f
#define SCALING 0.17677669529663687f   // 32^-0.5, applied POST-softmax
#define DEFER_THR 8.0f                 // exp2-domain defer-max threshold: p <= 2^8

__device__ __forceinline__ half8 mk8(unsigned a, unsigned b, unsigned c, unsigned d) {
  union { unsigned u[4]; half8 h; } z;
  z.u[0] = a; z.u[1] = b; z.u[2] = c; z.u[3] = d;
  return z.h;
}

// permlane32_swap semantics: a' = {a.lo, b.lo}, b' = {a.hi, b.hi}
// (vdst.hi <-> vsrc.lo). Builtin if available, shfl+select fallback otherwise.
__device__ __forceinline__ void plswap(unsigned& a, unsigned& b) {
#if __has_builtin(__builtin_amdgcn_permlane32_swap)
  uint2v r = __builtin_amdgcn_permlane32_swap(a, b, false, false);
  a = r[0]; b = r[1];
#else
  unsigned sa = (unsigned)__shfl_xor((int)a, 32);
  unsigned sb = (unsigned)__shfl_xor((int)b, 32);
  bool hi = (threadIdx.x & 32) != 0;
  unsigned na = hi ? sb : a;
  unsigned nb = hi ? b : sa;
  a = na; b = nb;
#endif
}
__device__ __forceinline__ float plswap_red_max(float x) {
  return fmaxf(x, __shfl_xor(x, 32));
}
__device__ __forceinline__ float plswap_red_add(float x) {
  return x + __shfl_xor(x, 32);
}

// sum of the two f16 halves of pk into acc (consistent with the f16 P fed to PV MFMA)
__device__ __forceinline__ float sum2(unsigned pk, float acc) {
  half2v a = __builtin_bit_cast(half2v, pk);
#if __has_builtin(__builtin_amdgcn_fdot2)
  half2v one; one[0] = (_Float16)1.f; one[1] = (_Float16)1.f;
  return __builtin_amdgcn_fdot2(a, one, acc, false);
#else
  return acc + (float)a[0] + (float)a[1];
#endif
}

// ---------------- Kernel 0: swizzle W into MFMA B-frag order (f16), Wq pre-scaled by L2E ----------------
__global__ __launch_bounds__(256) void prep_kernel(const float* __restrict__ Wq,
                                                   const float* __restrict__ Wk,
                                                   const float* __restrict__ Wv,
                                                   _Float16* __restrict__ wsw) {
  int gid = blockIdx.x * 256 + threadIdx.x;   // [0, 24576)
  int j    = gid & 7;
  int lane = (gid >> 3) & 63;
  int kc   = (gid >> 9) & 7;
  int half = (gid >> 12) & 1;
  int mat  = gid >> 13;
  const float* W = (mat == 0) ? Wq : ((mat == 1) ? Wk : Wv);
  int n = lane & 15, quad = lane >> 4;
  int e = kc * 32 + quad * 8 + j;
  int d = n + half * 16;
  float v = W[e * HD + d];
  if (mat == 0) v *= L2E;                     // exp2-domain scores for free
  wsw[gid] = (_Float16)v;
}

// ---------------- Kernel 1: fused QKV projection (x read ONCE, converted once) ----------------
// Each block: 64 rows, all three matrices (was grid.y=3 -> 3x x re-read = +33 MB HBM).
// V stored key-tiled: vt2[b][s>>3][d][s&7] so attn's PV A-frag loads are lane-contiguous.
__global__ __launch_bounds__(256) void qkv_kernel(const float* __restrict__ x,
                                                  const _Float16* __restrict__ wsw,
                                                  _Float16* __restrict__ qw,
                                                  _Float16* __restrict__ kw,
                                                  _Float16* __restrict__ vt2) {
  int lane = threadIdx.x & 63, wave = threadIdx.x >> 6;
  int n = lane & 15, quad = lane >> 4;
  int rowbase = blockIdx.x * 64 + wave * 16;

  floatx4 cq0 = {0,0,0,0}, cq1 = {0,0,0,0};
  floatx4 ck0 = {0,0,0,0}, ck1 = {0,0,0,0};
  floatx4 cv0 = {0,0,0,0}, cv1 = {0,0,0,0};

#pragma unroll
  for (int kc = 0; kc < 8; ++kc) {
    const float* xp = x + (rowbase + n) * EMB + kc * 32 + quad * 8;
    float4 xa = *(const float4*)(xp);
    float4 xb = *(const float4*)(xp + 4);
    half8 a;
    a[0] = (_Float16)xa.x; a[1] = (_Float16)xa.y; a[2] = (_Float16)xa.z; a[3] = (_Float16)xa.w;
    a[4] = (_Float16)xb.x; a[5] = (_Float16)xb.y; a[6] = (_Float16)xb.z; a[7] = (_Float16)xb.w;
    const _Float16* wp = wsw + (kc << 9) + (lane << 3);   // mat0/half0 base; wsw is 48 KB, L2-hot
    half8 bq0 = *(const half8*)(wp);
    half8 bq1 = *(const half8*)(wp + (8  << 9));
    half8 bk0 = *(const half8*)(wp + (16 << 9));
    half8 bk1 = *(const half8*)(wp + (24 << 9));
    half8 bv0 = *(const half8*)(wp + (32 << 9));
    half8 bv1 = *(const half8*)(wp + (40 << 9));
    cq0 = __builtin_amdgcn_mfma_f32_16x16x32_f16(a, bq0, cq0, 0, 0, 0);
    cq1 = __builtin_amdgcn_mfma_f32_16x16x32_f16(a, bq1, cq1, 0, 0, 0);
    ck0 = __builtin_amdgcn_mfma_f32_16x16x32_f16(a, bk0, ck0, 0, 0, 0);
    ck1 = __builtin_amdgcn_mfma_f32_16x16x32_f16(a, bk1, ck1, 0, 0, 0);
    cv0 = __builtin_amdgcn_mfma_f32_16x16x32_f16(a, bv0, cv0, 0, 0, 0);
    cv1 = __builtin_amdgcn_mfma_f32_16x16x32_f16(a, bv1, cv1, 0, 0, 0);
  }

  int b = rowbase >> 12;
  int s0 = rowbase & (SEQ - 1);
  _Float16* vbase = vt2 + (size_t)b * SEQ * HD;
#pragma unroll
  for (int r = 0; r < 4; ++r) {
    int row = rowbase + quad * 4 + r;
    qw[row * HD + n]      = (_Float16)cq0[r];
    qw[row * HD + n + 16] = (_Float16)cq1[r];
    kw[row * HD + n]      = (_Float16)ck0[r];
    kw[row * HD + n + 16] = (_Float16)ck1[r];
    int s = s0 + quad * 4 + r;
    int blk = (s >> 3) << 8, sl = s & 7;   // key-block base (8 keys x 32 d), slot
    vbase[blk + n * 8 + sl]        = (_Float16)cv0[r];
    vbase[blk + (n + 16) * 8 + sl] = (_Float16)cv1[r];
  }
}

// ---------------- Kernel 2: flash attention on 32x32x16 MFMA, O^T orientation ----------------
// 1024 blocks x 256 thr (4 waves) = exactly 4 resident blocks/CU, one residency pass.
// Wave owns 32 q-rows; block's 4 waves share keys [sp*512, +512) in 16 tiles of 32.
// Softmax: exp2-domain, defer-max (skip o-rescale unless max grows > THR), permlane32_swap
// for P-frag exchange, f16-dot2 l partials merged once at the end.
__global__ __launch_bounds__(256, 4) void attn_kernel(const _Float16* __restrict__ q,
                                                      const _Float16* __restrict__ k,
                                                      const _Float16* __restrict__ vt2,
                                                      _Float16* __restrict__ Op,
                                                      float* __restrict__ Mp,
                                                      float* __restrict__ Lp) {
  const int t = threadIdx.x;
  const int w = t >> 6, lane = t & 63;
  const int n2 = lane & 31, h = lane >> 5;
  const int qb = blockIdx.x & 127;
  const int sp = blockIdx.x >> 7;
  const int b = qb >> 5;
  const int qrow0 = qb * 128 + w * 32;
  const int key0 = sp * KRANGE;

  const _Float16* kb = k   + (size_t)(b * SEQ + key0) * HD;
  const _Float16* vb = vt2 + (size_t)b * SEQ * HD + (size_t)key0 * HD;  // key*32 elems

  // Q^T B-frags (pre-scaled by L2E): B[k=d][n=qrow=n2]
  half8 qf0 = *(const half8*)(q + (qrow0 + n2) * HD + h * 8);
  half8 qf1 = *(const half8*)(q + (qrow0 + n2) * HD + 16 + h * 8);

  floatx16 o;
#pragma unroll
  for (int r = 0; r < 16; ++r) o[r] = 0.f;
  const floatx16 zero16 = o;
  float m = -__builtin_huge_valf();      // deferred reference max (exp2 domain)
  float mtrue = -__builtin_huge_valf();  // true running max (for epilogue rescale)
  float l = 0.f;                         // own-16-keys partial; pair-merged at end

  // prefetch tile 0. V^T A-frag: A[m=d=n2][k=key=8h+j] -> vtile + h*256 + n2*8 (+512)
  half8 ka0 = *(const half8*)(kb + (size_t)n2 * HD + h * 8);
  half8 ka1 = *(const half8*)(kb + (size_t)n2 * HD + 16 + h * 8);
  half8 va0 = *(const half8*)(vb + h * 256 + n2 * 8);
  half8 va1 = *(const half8*)(vb + 512 + h * 256 + n2 * 8);

#pragma unroll 4
  for (int kt = 0; kt < NT; ++kt) {
    // issue tile kt+1 loads first (wrap-around on last iter: harmless re-load, no branch)
    int nxt = (kt + 1) & (NT - 1);
    const _Float16* kn = kb + (size_t)(nxt * 32 + n2) * HD;
    const _Float16* vn = vb + nxt * 1024;
    half8 nka0 = *(const half8*)(kn + h * 8);
    half8 nka1 = *(const half8*)(kn + 16 + h * 8);
    half8 nva0 = *(const half8*)(vn + h * 256 + n2 * 8);
    half8 nva1 = *(const half8*)(vn + 512 + h * 256 + n2 * 8);

    // S^T tile [32 keys x 32 qrows], accumulate over the two d-halves
    floatx16 s = __builtin_amdgcn_mfma_f32_32x32x16_f16(ka0, qf0, zero16, 0, 0, 0);
    s = __builtin_amdgcn_mfma_f32_32x32x16_f16(ka1, qf1, s, 0, 0, 0);

    // per-lane max over 16 scores (all of q-row n2), then merge the lane^32 partner
    floatx4 s0 = {s[0], s[1], s[2], s[3]};
    floatx4 s1 = {s[4], s[5], s[6], s[7]};
    floatx4 s2 = {s[8], s[9], s[10], s[11]};
    floatx4 s3 = {s[12], s[13], s[14], s[15]};
    floatx4 t01 = __builtin_elementwise_max(s0, s1);
    floatx4 t23 = __builtin_elementwise_max(s2, s3);
    floatx4 t4  = __builtin_elementwise_max(t01, t23);
    float mm = fmaxf(fmaxf(t4[0], t4[1]), fmaxf(t4[2], t4[3]));
    mm = plswap_red_max(mm);
    mtrue = fmaxf(mtrue, mm);

    // defer-max: only rescale when some row's max grew past THR (wave-uniform branch)
    if (__any(mm > m + DEFER_THR)) {
      float mnew = fmaxf(m, mm);
      float alpha = __builtin_amdgcn_exp2f(m - mnew);
      m = mnew;
#pragma unroll
      for (int r = 0; r < 16; ++r) o[r] *= alpha;
      l *= alpha;
    }

    // p = exp2(s - m) <= 2^THR, pack consecutive-key pairs
    unsigned pk[8];
#pragma unroll
    for (int g = 0; g < 8; ++g) {
      float p0 = __builtin_amdgcn_exp2f(s[2 * g] - m);
      float p1 = __builtin_amdgcn_exp2f(s[2 * g + 1] - m);
      pk[g] = __builtin_bit_cast(unsigned, __builtin_amdgcn_cvt_pkrtz(p0, p1));
    }

    // l partial: own 16 keys via f16 dot2 (partner merged once after the loop)
    float lA = sum2(pk[3], sum2(pk[2], sum2(pk[1], sum2(pk[0], 0.f))));
    float lB = sum2(pk[7], sum2(pk[6], sum2(pk[5], sum2(pk[4], 0.f))));
    l += lA + lB;

    // P^T B-frags via permlane32_swap: swap(pk0,pk2) -> B0 words {0,2}; (pk1,pk3) -> {1,3}
    unsigned b00 = pk[0], b02 = pk[2]; plswap(b00, b02);
    unsigned b01 = pk[1], b03 = pk[3]; plswap(b01, b03);
    unsigned b10 = pk[4], b12 = pk[6]; plswap(b10, b12);
    unsigned b11 = pk[5], b13 = pk[7]; plswap(b11, b13);

    // O^T += V^T · P^T  (two key halves)
    o = __builtin_amdgcn_mfma_f32_32x32x16_f16(va0, mk8(b00, b01, b02, b03), o, 0, 0, 0);
    o = __builtin_amdgcn_mfma_f32_32x32x16_f16(va1, mk8(b10, b11, b12, b13), o, 0, 0, 0);

    ka0 = nka0; ka1 = nka1; va0 = nva0; va1 = nva1;
  }

  // epilogue: rescale to the true max so f16 Op cannot overflow (p_eff <= 1)
  float scale = __builtin_amdgcn_exp2f(m - mtrue);
  l *= scale;
  l = plswap_red_add(l);   // own + partner halves

  // lane(n2,h) reg r -> qrow=n2, d=(r&3)+8*(r>>2)+4h; half4 stores
  size_t obase = ((size_t)(sp * NQROW + qrow0) + n2) * 32;
#pragma unroll
  for (int bb = 0; bb < 4; ++bb) {
    half4v pv;
    pv[0] = (_Float16)(o[4 * bb + 0] * scale);
    pv[1] = (_Float16)(o[4 * bb + 1] * scale);
    pv[2] = (_Float16)(o[4 * bb + 2] * scale);
    pv[3] = (_Float16)(o[4 * bb + 3] * scale);
    *(half4v*)&Op[obase + 8 * bb + 4 * h] = pv;
  }
  if (h == 0) {
    int mi = sp * NQROW + qrow0 + n2;
    Mp[mi] = mtrue;
    Lp[mi] = l;
  }
}

// ---------------- Kernel 3: merge the 8 key-splits, normalize, scale ----------------
__global__ __launch_bounds__(256) void combine_kernel(const _Float16* __restrict__ Op,
                                                      const float* __restrict__ Mp,
                                                      const float* __restrict__ Lp,
                                                      float* __restrict__ out) {
  int gid = blockIdx.x * 256 + threadIdx.x;   // [0, 131072)
  int dc = gid & 7, qrow = gid >> 3;
  float mv[NSPLIT];
  float ms = -__builtin_huge_valf();
#pragma unroll
  for (int sp = 0; sp < NSPLIT; ++sp) {
    mv[sp] = Mp[sp * NQROW + qrow];
    ms = fmaxf(ms, mv[sp]);
  }
  float L = 0.f;
  floatx4 O = {0.f, 0.f, 0.f, 0.f};
#pragma unroll
  for (int sp = 0; sp < NSPLIT; ++sp) {
    float ww = __builtin_amdgcn_exp2f(mv[sp] - ms);
    L += ww * Lp[sp * NQROW + qrow];
    half4v ov = *(const half4v*)&Op[((size_t)(sp * NQROW + qrow)) * 32 + dc * 4];
#pragma unroll
    for (int r = 0; r < 4; ++r) O[r] += ww * (float)ov[r];
  }
  float inv = SCALING / L;
  floatx4 res = {O[0] * inv, O[1] * inv, O[2] * inv, O[3] * inv};
  *(floatx4*)&out[qrow * HD + dc * 4] = res;
}

extern "C" void kernel_launch(void* const* d_in, const int* in_sizes, int n_in,
                              void* d_out, int out_size, void* d_ws, size_t ws_size,
                              hipStream_t stream) {
  const float* x  = (const float*)d_in[0];
  const float* Wq = (const float*)d_in[1];
  const float* Wk = (const float*)d_in[2];
  const float* Wv = (const float*)d_in[3];
  float* out = (float*)d_out;

  _Float16* wsw = (_Float16*)d_ws;          // 24576 f16
  _Float16* qw  = wsw + 24576;              // [16384][32]
  _Float16* kw  = qw + NQROW * HD;          // [16384][32]
  _Float16* vt2 = kw + NQROW * HD;          // [4][512][32][8] key-tiled V
  _Float16* Op  = vt2 + NQROW * HD;         // [8][16384][32] f16 (8 MB)
  float* Mp = (float*)(Op + (size_t)NSPLIT * NQROW * 32);  // [8][16384]
  float* Lp = Mp + NSPLIT * NQROW;                         // [8][16384]

  prep_kernel<<<96, 256, 0, stream>>>(Wq, Wk, Wv, wsw);
  qkv_kernel<<<256, 256, 0, stream>>>(x, wsw, qw, kw, vt2);
  attn_kernel<<<1024, 256, 0, stream>>>(qw, kw, vt2, Op, Mp, Lp);
  combine_kernel<<<512, 256, 0, stream>>>(Op, Mp, Lp, out);
}